// Round 1
// baseline (194.829 us; speedup 1.0000x reference)
//
#include <hip/hip_runtime.h>
#include <math.h>

#define GRP   4
#define K     9
#define KS    3
#define PAD   1
#define C_IN  64
#define C_OUT 64
#define CG    16
#define HH    128
#define WW    128
#define BB    4
#define HW    (HH*WW)
#define OMG   (3*K)   // 27 om channels per group
#define OMGP  28      // padded

// ---------------- Kernel 1: fused om 1x1-conv + modulated deformable conv ----
// grid: B*G*64 blocks (each block: 256 consecutive pixels of one (b,g) plane)
__global__ __launch_bounds__(256) void dcn_fused(
    const float* __restrict__ x,        // [B,64,H,W]
    const float* __restrict__ w_om,     // [108,64]
    const float* __restrict__ b_om,     // [108]
    const float* __restrict__ dcn_w,    // [G,16,16,3,3]
    const float* __restrict__ dcn_b,    // [G,16]
    const float* __restrict__ offset_scale, // [1]
    float* __restrict__ out)            // [B,64,H,W]  (conv result, pre-GN)
{
    const int tid   = threadIdx.x;
    const int blk   = blockIdx.x;
    const int bg    = blk >> 6;
    const int chunk = blk & 63;
    const int b     = bg >> 2;
    const int g     = bg & 3;
    const int pix   = chunk * 256 + tid;      // [0,16384)
    const int h     = pix >> 7;
    const int w     = pix & 127;

    // LDS: om weights laid out [c][o_padded], dcn weights [k][ci][co]
    __shared__ float s_wom[C_IN * OMGP];      // 64*28*4 = 7168 B
    __shared__ float s_w[K * CG * CG];        // 9*16*16*4 = 9216 B
    __shared__ float s_bom[OMG];
    __shared__ float s_b[CG];

    for (int i = tid; i < C_IN * OMGP; i += 256) {
        int c = i / OMGP, o = i - c * OMGP;
        s_wom[i] = (o < OMG) ? w_om[(g * OMG + o) * C_IN + c] : 0.0f;
    }
    for (int i = tid; i < K * CG * CG; i += 256) {
        int co = i & 15, ci = (i >> 4) & 15, k = i >> 8;
        s_w[i] = dcn_w[((g * CG + co) * CG + ci) * K + k];
    }
    if (tid < OMG) s_bom[tid] = b_om[g * OMG + tid];
    if (tid < CG)  s_b[tid]   = dcn_b[g * CG + tid];
    __syncthreads();

    // ---- stage 1: om[o] = sum_c x[b,c,h,w] * w_om[g*27+o, c] + b_om ----
    float om[OMGP];
    #pragma unroll
    for (int o = 0; o < OMGP; ++o) om[o] = 0.0f;
    const float* xp = x + (size_t)b * C_IN * HW + pix;
    for (int c = 0; c < C_IN; ++c) {
        float xv = xp[(size_t)c * HW];
        const float4* wp = (const float4*)&s_wom[c * OMGP];
        #pragma unroll
        for (int q = 0; q < 7; ++q) {
            float4 w4 = wp[q];
            om[q*4+0] += w4.x * xv;
            om[q*4+1] += w4.y * xv;
            om[q*4+2] += w4.z * xv;
            om[q*4+3] += w4.w * xv;
        }
    }
    #pragma unroll
    for (int o = 0; o < OMG; ++o) om[o] += s_bom[o];

    const float scale = offset_scale[0];

    // ---- stage 2: deformable conv ----
    float acc[CG];
    #pragma unroll
    for (int co = 0; co < CG; ++co) acc[co] = s_b[co];

    const float* xg = x + ((size_t)b * C_IN + g * CG) * HW;

    #pragma unroll
    for (int k = 0; k < K; ++k) {
        const int ky = k / KS, kx = k % KS;
        float py = (float)(h - PAD + ky) + om[2*k]     * scale;
        float px = (float)(w - PAD + kx) + om[2*k + 1] * scale;
        float m  = 1.0f / (1.0f + expf(-om[2*K + k]));

        float y0f = floorf(py), x0f = floorf(px);
        int   y0  = (int)y0f,   x0  = (int)x0f;
        float wy1 = py - y0f,   wx1 = px - x0f;
        float wy0 = 1.0f - wy1, wx0 = 1.0f - wx1;

        bool vy0 = (y0   >= 0) && (y0   <= HH - 1);
        bool vy1 = (y0+1 >= 0) && (y0+1 <= HH - 1);
        bool vx0 = (x0   >= 0) && (x0   <= WW - 1);
        bool vx1 = (x0+1 >= 0) && (x0+1 <= WW - 1);

        int yi0 = min(max(y0,     0), HH - 1);
        int yi1 = min(max(y0 + 1, 0), HH - 1);
        int xi0 = min(max(x0,     0), WW - 1);
        int xi1 = min(max(x0 + 1, 0), WW - 1);

        float w00 = (vy0 && vx0) ? wy0 * wx0 * m : 0.0f;
        float w01 = (vy0 && vx1) ? wy0 * wx1 * m : 0.0f;
        float w10 = (vy1 && vx0) ? wy1 * wx0 * m : 0.0f;
        float w11 = (vy1 && vx1) ? wy1 * wx1 * m : 0.0f;

        int o00 = yi0 * WW + xi0, o01 = yi0 * WW + xi1;
        int o10 = yi1 * WW + xi0, o11 = yi1 * WW + xi1;

        #pragma unroll
        for (int ci = 0; ci < CG; ++ci) {
            const float* xc = xg + (size_t)ci * HW;
            float v = w00 * xc[o00] + w01 * xc[o01]
                    + w10 * xc[o10] + w11 * xc[o11];
            const float4* wp = (const float4*)&s_w[(k * CG + ci) * CG];
            #pragma unroll
            for (int q = 0; q < 4; ++q) {
                float4 w4 = wp[q];
                acc[q*4+0] += v * w4.x;
                acc[q*4+1] += v * w4.y;
                acc[q*4+2] += v * w4.z;
                acc[q*4+3] += v * w4.w;
            }
        }
    }

    float* op = out + ((size_t)b * C_OUT + g * CG) * HW + pix;
    #pragma unroll
    for (int co = 0; co < CG; ++co) op[(size_t)co * HW] = acc[co];
}

// ---------------- Kernel 2: GroupNorm stats per (b,g) ------------------------
// The 16 channels of one (b,g) are contiguous: 262144 floats starting at bg*CG*HW.
__global__ __launch_bounds__(256) void gn_stats(const float* __restrict__ out,
                                                float* __restrict__ stats)
{
    const int bg = blockIdx.x;  // 16 blocks
    const float4* p = (const float4*)(out + (size_t)bg * CG * HW);
    float s = 0.0f, ss = 0.0f;
    for (int i = threadIdx.x; i < CG * HW / 4; i += 256) {
        float4 v = p[i];
        s  += v.x + v.y + v.z + v.w;
        ss += v.x*v.x + v.y*v.y + v.z*v.z + v.w*v.w;
    }
    __shared__ float ls[256], lss[256];
    ls[threadIdx.x] = s; lss[threadIdx.x] = ss;
    __syncthreads();
    for (int st = 128; st > 0; st >>= 1) {
        if (threadIdx.x < st) {
            ls[threadIdx.x]  += ls[threadIdx.x + st];
            lss[threadIdx.x] += lss[threadIdx.x + st];
        }
        __syncthreads();
    }
    if (threadIdx.x == 0) {
        float n   = (float)(CG * HW);
        float mu  = ls[0] / n;
        float var = lss[0] / n - mu * mu;
        stats[bg * 2]     = mu;
        stats[bg * 2 + 1] = rsqrtf(var + 1e-5f);
    }
}

// ---------------- Kernel 3: in-place GroupNorm apply + exact GELU ------------
__global__ __launch_bounds__(256) void gn_gelu(float* __restrict__ out,
                                               const float* __restrict__ stats,
                                               const float* __restrict__ gn_w,
                                               const float* __restrict__ gn_b)
{
    const int idx = blockIdx.x * 256 + threadIdx.x;   // float4 index
    const int bc  = idx >> 12;                        // b*64 + c   (HW/4 = 4096)
    const int c   = bc & 63;
    const int bg  = ((bc >> 6) << 2) + (c >> 4);

    float mu = stats[bg * 2];
    float rs = stats[bg * 2 + 1];
    float sw = gn_w[c] * rs;
    float sb = gn_b[c] - mu * sw;

    float4 v = ((const float4*)out)[idx];
    float r[4] = {v.x, v.y, v.z, v.w};
    #pragma unroll
    for (int j = 0; j < 4; ++j) {
        float t = r[j] * sw + sb;
        r[j] = t * 0.5f * (1.0f + erff(t * 0.70710678118654752f));
    }
    ((float4*)out)[idx] = make_float4(r[0], r[1], r[2], r[3]);
}

extern "C" void kernel_launch(void* const* d_in, const int* in_sizes, int n_in,
                              void* d_out, int out_size, void* d_ws, size_t ws_size,
                              hipStream_t stream) {
    const float* x            = (const float*)d_in[0];
    const float* w_om         = (const float*)d_in[1];
    const float* b_om         = (const float*)d_in[2];
    const float* dcn_w        = (const float*)d_in[3];
    const float* dcn_b        = (const float*)d_in[4];
    const float* gn_w         = (const float*)d_in[5];
    const float* gn_b         = (const float*)d_in[6];
    const float* offset_scale = (const float*)d_in[7];
    float* out   = (float*)d_out;
    float* stats = (float*)d_ws;   // 32 floats

    dcn_fused<<<BB * GRP * 64, 256, 0, stream>>>(x, w_om, b_om, dcn_w, dcn_b,
                                                 offset_scale, out);
    gn_stats<<<BB * GRP, 256, 0, stream>>>(out, stats);
    gn_gelu<<<(BB * C_OUT * HW / 4) / 256, 256, 0, stream>>>(out, stats, gn_w, gn_b);
}

// Round 2
// 94.152 us; speedup vs baseline: 2.0693x; 2.0693x over previous
//
#include <hip/hip_runtime.h>
#include <math.h>

#define GRP   4
#define K     9
#define KS    3
#define PAD   1
#define C_IN  64
#define C_OUT 64
#define CG    16
#define HH    128
#define WW    128
#define BB    4
#define HW    (HH*WW)
#define OMG   (3*K)   // 27 om channels per group
#define OMGP  28      // padded

#define XT_FLOATS ((size_t)BB * GRP * HW * CG)         // 4,194,304
#define PART_OFF  XT_FLOATS                            // 2048 floats (1024 blk * 2)
#define STATS_OFF (XT_FLOATS + 2048)                   // 32 floats
#define NEW_WS_BYTES ((STATS_OFF + 32) * sizeof(float))

// ============================ NEW PATH =======================================

// ---- Kernel T: x[B,64,H,W] -> xt[B*G, HW, 16] (pixel-major channels) --------
__global__ __launch_bounds__(256) void transpose_x(const float* __restrict__ x,
                                                   float* __restrict__ xt)
{
    const int t   = blockIdx.x * 256 + threadIdx.x;    // 262144 threads
    const int pix = t & (HW - 1);
    const int bg  = t >> 14;
    const int b   = bg >> 2;
    const int g   = bg & 3;
    const float* xs = x + ((size_t)b * C_IN + g * CG) * HW + pix;
    float v[CG];
    #pragma unroll
    for (int ci = 0; ci < CG; ++ci) v[ci] = xs[(size_t)ci * HW];
    float4* dst = (float4*)(xt + ((size_t)bg * HW + pix) * CG);
    dst[0] = make_float4(v[0], v[1], v[2], v[3]);
    dst[1] = make_float4(v[4], v[5], v[6], v[7]);
    dst[2] = make_float4(v[8], v[9], v[10], v[11]);
    dst[3] = make_float4(v[12], v[13], v[14], v[15]);
}

// ---- Kernel 1: fused om 1x1-conv + deform conv + GN partial stats -----------
__global__ __launch_bounds__(256) void dcn_fused2(
    const float* __restrict__ x,        // [B,64,H,W]   (for om stage)
    const float* __restrict__ xt,       // [B*G,HW,16]  (for sampling)
    const float* __restrict__ w_om,     // [108,64]
    const float* __restrict__ b_om,     // [108]
    const float* __restrict__ dcn_w,    // [G,16,16,3,3]
    const float* __restrict__ dcn_b,    // [G,16]
    const float* __restrict__ offset_scale,
    float* __restrict__ out,            // [B,64,H,W]  (conv result, pre-GN)
    float* __restrict__ partials)       // [1024*2]
{
    const int tid = threadIdx.x;
    const int blk = blockIdx.x;
    // XCD-friendly remap: blk = 16*q + 8*r + j  ->  bg = 2*j + r, chunk = q
    const int j     = blk & 7;
    const int r     = (blk >> 3) & 1;
    const int chunk = blk >> 4;
    const int bg    = j * 2 + r;
    const int b     = bg >> 2;
    const int g     = bg & 3;
    const int pix   = chunk * 256 + tid;
    const int h     = pix >> 7;
    const int w     = pix & 127;

    __shared__ float s_wom[C_IN * OMGP];
    __shared__ float s_w[K * CG * CG];
    __shared__ float s_bom[OMG];
    __shared__ float s_b[CG];
    __shared__ float red[512];

    for (int i = tid; i < C_IN * OMGP; i += 256) {
        int c = i / OMGP, o = i - c * OMGP;
        s_wom[i] = (o < OMG) ? w_om[(g * OMG + o) * C_IN + c] : 0.0f;
    }
    for (int i = tid; i < K * CG * CG; i += 256) {
        int co = i & 15, ci = (i >> 4) & 15, k = i >> 8;
        s_w[i] = dcn_w[((g * CG + co) * CG + ci) * K + k];
    }
    if (tid < OMG) s_bom[tid] = b_om[g * OMG + tid];
    if (tid < CG)  s_b[tid]   = dcn_b[g * CG + tid];
    __syncthreads();

    // ---- stage 1: om = W_om . x ----
    float om[OMGP];
    #pragma unroll
    for (int o = 0; o < OMGP; ++o) om[o] = 0.0f;
    const float* xp = x + (size_t)b * C_IN * HW + pix;
    for (int c = 0; c < C_IN; ++c) {
        float xv = xp[(size_t)c * HW];
        const float4* wp = (const float4*)&s_wom[c * OMGP];
        #pragma unroll
        for (int q = 0; q < 7; ++q) {
            float4 w4 = wp[q];
            om[q*4+0] += w4.x * xv;
            om[q*4+1] += w4.y * xv;
            om[q*4+2] += w4.z * xv;
            om[q*4+3] += w4.w * xv;
        }
    }
    #pragma unroll
    for (int o = 0; o < OMG; ++o) om[o] += s_bom[o];

    const float scale = offset_scale[0];

    // ---- stage 2: deformable conv from xt ----
    float acc[CG];
    #pragma unroll
    for (int co = 0; co < CG; ++co) acc[co] = s_b[co];

    const float* xtg = xt + (size_t)bg * HW * CG;

    #pragma unroll
    for (int k = 0; k < K; ++k) {
        const int ky = k / KS, kx = k % KS;
        float py = (float)(h - PAD + ky) + om[2*k]     * scale;
        float px = (float)(w - PAD + kx) + om[2*k + 1] * scale;
        float m  = 1.0f / (1.0f + expf(-om[2*K + k]));

        float y0f = floorf(py), x0f = floorf(px);
        int   y0  = (int)y0f,   x0  = (int)x0f;
        float wy1 = py - y0f,   wx1 = px - x0f;
        float wy0 = 1.0f - wy1, wx0 = 1.0f - wx1;

        bool vy0 = (y0   >= 0) && (y0   <= HH - 1);
        bool vy1 = (y0+1 >= 0) && (y0+1 <= HH - 1);
        bool vx0 = (x0   >= 0) && (x0   <= WW - 1);
        bool vx1 = (x0+1 >= 0) && (x0+1 <= WW - 1);

        int yi0 = min(max(y0,     0), HH - 1);
        int yi1 = min(max(y0 + 1, 0), HH - 1);
        int xi0 = min(max(x0,     0), WW - 1);
        int xi1 = min(max(x0 + 1, 0), WW - 1);

        float w00 = (vy0 && vx0) ? wy0 * wx0 * m : 0.0f;
        float w01 = (vy0 && vx1) ? wy0 * wx1 * m : 0.0f;
        float w10 = (vy1 && vx0) ? wy1 * wx0 * m : 0.0f;
        float w11 = (vy1 && vx1) ? wy1 * wx1 * m : 0.0f;

        const float4* p00 = (const float4*)(xtg + (size_t)(yi0 * WW + xi0) * CG);
        const float4* p01 = (const float4*)(xtg + (size_t)(yi0 * WW + xi1) * CG);
        const float4* p10 = (const float4*)(xtg + (size_t)(yi1 * WW + xi0) * CG);
        const float4* p11 = (const float4*)(xtg + (size_t)(yi1 * WW + xi1) * CG);

        float vv[CG];
        #pragma unroll
        for (int q = 0; q < 4; ++q) {
            float4 t00 = p00[q], t01 = p01[q], t10 = p10[q], t11 = p11[q];
            vv[q*4+0] = w00*t00.x + w01*t01.x + w10*t10.x + w11*t11.x;
            vv[q*4+1] = w00*t00.y + w01*t01.y + w10*t10.y + w11*t11.y;
            vv[q*4+2] = w00*t00.z + w01*t01.z + w10*t10.z + w11*t11.z;
            vv[q*4+3] = w00*t00.w + w01*t01.w + w10*t10.w + w11*t11.w;
        }
        #pragma unroll
        for (int ci = 0; ci < CG; ++ci) {
            float v = vv[ci];
            const float4* wp = (const float4*)&s_w[(k * CG + ci) * CG];
            #pragma unroll
            for (int q = 0; q < 4; ++q) {
                float4 w4 = wp[q];
                acc[q*4+0] += v * w4.x;
                acc[q*4+1] += v * w4.y;
                acc[q*4+2] += v * w4.z;
                acc[q*4+3] += v * w4.w;
            }
        }
    }

    float* op = out + ((size_t)b * C_OUT + g * CG) * HW + pix;
    float s = 0.0f, ss = 0.0f;
    #pragma unroll
    for (int co = 0; co < CG; ++co) {
        op[(size_t)co * HW] = acc[co];
        s  += acc[co];
        ss += acc[co] * acc[co];
    }

    // ---- GN partial reduction for this block ----
    red[tid] = s; red[256 + tid] = ss;
    __syncthreads();
    for (int st = 128; st > 0; st >>= 1) {
        if (tid < st) {
            red[tid]       += red[tid + st];
            red[256 + tid] += red[256 + tid + st];
        }
        __syncthreads();
    }
    if (tid == 0) {
        partials[(bg * 64 + chunk) * 2]     = red[0];
        partials[(bg * 64 + chunk) * 2 + 1] = red[256];
    }
}

// ---- Kernel 2: finalize GN stats (16 blocks x 64 lanes, deterministic) ------
__global__ __launch_bounds__(64) void gn_finalize(const float* __restrict__ partials,
                                                  float* __restrict__ stats)
{
    const int bg = blockIdx.x;
    const int t  = threadIdx.x;
    float s  = partials[(bg * 64 + t) * 2];
    float ss = partials[(bg * 64 + t) * 2 + 1];
    #pragma unroll
    for (int off = 32; off > 0; off >>= 1) {
        s  += __shfl_down(s, off);
        ss += __shfl_down(ss, off);
    }
    if (t == 0) {
        float n   = (float)(CG * HW);
        float mu  = s / n;
        float var = ss / n - mu * mu;
        stats[bg * 2]     = mu;
        stats[bg * 2 + 1] = rsqrtf(var + 1e-5f);
    }
}

// ---- Kernel 3: in-place GroupNorm apply + exact GELU ------------------------
__global__ __launch_bounds__(256) void gn_gelu(float* __restrict__ out,
                                               const float* __restrict__ stats,
                                               const float* __restrict__ gn_w,
                                               const float* __restrict__ gn_b)
{
    const int idx = blockIdx.x * 256 + threadIdx.x;   // float4 index
    const int bc  = idx >> 12;                        // b*64 + c
    const int c   = bc & 63;
    const int bg  = ((bc >> 6) << 2) + (c >> 4);

    float mu = stats[bg * 2];
    float rs = stats[bg * 2 + 1];
    float sw = gn_w[c] * rs;
    float sb = gn_b[c] - mu * sw;

    float4 v = ((const float4*)out)[idx];
    float rr[4] = {v.x, v.y, v.z, v.w};
    #pragma unroll
    for (int jj = 0; jj < 4; ++jj) {
        float t = rr[jj] * sw + sb;
        rr[jj] = t * 0.5f * (1.0f + erff(t * 0.70710678118654752f));
    }
    ((float4*)out)[idx] = make_float4(rr[0], rr[1], rr[2], rr[3]);
}

// ============================ FALLBACK PATH (round-1, proven) ================

__global__ __launch_bounds__(256) void dcn_fused_fb(
    const float* __restrict__ x, const float* __restrict__ w_om,
    const float* __restrict__ b_om, const float* __restrict__ dcn_w,
    const float* __restrict__ dcn_b, const float* __restrict__ offset_scale,
    float* __restrict__ out)
{
    const int tid = threadIdx.x;
    const int blk = blockIdx.x;
    const int bg = blk >> 6, chunk = blk & 63;
    const int b = bg >> 2, g = bg & 3;
    const int pix = chunk * 256 + tid;
    const int h = pix >> 7, w = pix & 127;

    __shared__ float s_wom[C_IN * OMGP];
    __shared__ float s_w[K * CG * CG];
    __shared__ float s_bom[OMG];
    __shared__ float s_b[CG];

    for (int i = tid; i < C_IN * OMGP; i += 256) {
        int c = i / OMGP, o = i - c * OMGP;
        s_wom[i] = (o < OMG) ? w_om[(g * OMG + o) * C_IN + c] : 0.0f;
    }
    for (int i = tid; i < K * CG * CG; i += 256) {
        int co = i & 15, ci = (i >> 4) & 15, k = i >> 8;
        s_w[i] = dcn_w[((g * CG + co) * CG + ci) * K + k];
    }
    if (tid < OMG) s_bom[tid] = b_om[g * OMG + tid];
    if (tid < CG)  s_b[tid]   = dcn_b[g * CG + tid];
    __syncthreads();

    float om[OMGP];
    #pragma unroll
    for (int o = 0; o < OMGP; ++o) om[o] = 0.0f;
    const float* xp = x + (size_t)b * C_IN * HW + pix;
    for (int c = 0; c < C_IN; ++c) {
        float xv = xp[(size_t)c * HW];
        const float4* wp = (const float4*)&s_wom[c * OMGP];
        #pragma unroll
        for (int q = 0; q < 7; ++q) {
            float4 w4 = wp[q];
            om[q*4+0] += w4.x * xv; om[q*4+1] += w4.y * xv;
            om[q*4+2] += w4.z * xv; om[q*4+3] += w4.w * xv;
        }
    }
    #pragma unroll
    for (int o = 0; o < OMG; ++o) om[o] += s_bom[o];

    const float scale = offset_scale[0];
    float acc[CG];
    #pragma unroll
    for (int co = 0; co < CG; ++co) acc[co] = s_b[co];
    const float* xg = x + ((size_t)b * C_IN + g * CG) * HW;

    #pragma unroll
    for (int k = 0; k < K; ++k) {
        const int ky = k / KS, kx = k % KS;
        float py = (float)(h - PAD + ky) + om[2*k] * scale;
        float px = (float)(w - PAD + kx) + om[2*k + 1] * scale;
        float m = 1.0f / (1.0f + expf(-om[2*K + k]));
        float y0f = floorf(py), x0f = floorf(px);
        int y0 = (int)y0f, x0 = (int)x0f;
        float wy1 = py - y0f, wx1 = px - x0f;
        float wy0 = 1.0f - wy1, wx0 = 1.0f - wx1;
        bool vy0 = (y0 >= 0) && (y0 <= HH-1);
        bool vy1 = (y0+1 >= 0) && (y0+1 <= HH-1);
        bool vx0 = (x0 >= 0) && (x0 <= WW-1);
        bool vx1 = (x0+1 >= 0) && (x0+1 <= WW-1);
        int yi0 = min(max(y0, 0), HH-1), yi1 = min(max(y0+1, 0), HH-1);
        int xi0 = min(max(x0, 0), WW-1), xi1 = min(max(x0+1, 0), WW-1);
        float w00 = (vy0 && vx0) ? wy0*wx0*m : 0.0f;
        float w01 = (vy0 && vx1) ? wy0*wx1*m : 0.0f;
        float w10 = (vy1 && vx0) ? wy1*wx0*m : 0.0f;
        float w11 = (vy1 && vx1) ? wy1*wx1*m : 0.0f;
        int o00 = yi0*WW+xi0, o01 = yi0*WW+xi1, o10 = yi1*WW+xi0, o11 = yi1*WW+xi1;
        #pragma unroll
        for (int ci = 0; ci < CG; ++ci) {
            const float* xc = xg + (size_t)ci * HW;
            float v = w00*xc[o00] + w01*xc[o01] + w10*xc[o10] + w11*xc[o11];
            const float4* wp = (const float4*)&s_w[(k * CG + ci) * CG];
            #pragma unroll
            for (int q = 0; q < 4; ++q) {
                float4 w4 = wp[q];
                acc[q*4+0] += v * w4.x; acc[q*4+1] += v * w4.y;
                acc[q*4+2] += v * w4.z; acc[q*4+3] += v * w4.w;
            }
        }
    }
    float* op = out + ((size_t)b * C_OUT + g * CG) * HW + pix;
    #pragma unroll
    for (int co = 0; co < CG; ++co) op[(size_t)co * HW] = acc[co];
}

__global__ __launch_bounds__(256) void gn_stats_fb(const float* __restrict__ out,
                                                   float* __restrict__ stats)
{
    const int bg = blockIdx.x;
    const float4* p = (const float4*)(out + (size_t)bg * CG * HW);
    float s = 0.0f, ss = 0.0f;
    for (int i = threadIdx.x; i < CG * HW / 4; i += 256) {
        float4 v = p[i];
        s  += v.x + v.y + v.z + v.w;
        ss += v.x*v.x + v.y*v.y + v.z*v.z + v.w*v.w;
    }
    __shared__ float ls[256], lss[256];
    ls[threadIdx.x] = s; lss[threadIdx.x] = ss;
    __syncthreads();
    for (int st = 128; st > 0; st >>= 1) {
        if (threadIdx.x < st) {
            ls[threadIdx.x]  += ls[threadIdx.x + st];
            lss[threadIdx.x] += lss[threadIdx.x + st];
        }
        __syncthreads();
    }
    if (threadIdx.x == 0) {
        float n = (float)(CG * HW);
        float mu = ls[0] / n;
        float var = lss[0] / n - mu * mu;
        stats[bg * 2] = mu;
        stats[bg * 2 + 1] = rsqrtf(var + 1e-5f);
    }
}

// ============================ launch =========================================

extern "C" void kernel_launch(void* const* d_in, const int* in_sizes, int n_in,
                              void* d_out, int out_size, void* d_ws, size_t ws_size,
                              hipStream_t stream) {
    const float* x            = (const float*)d_in[0];
    const float* w_om         = (const float*)d_in[1];
    const float* b_om         = (const float*)d_in[2];
    const float* dcn_w        = (const float*)d_in[3];
    const float* dcn_b        = (const float*)d_in[4];
    const float* gn_w         = (const float*)d_in[5];
    const float* gn_b         = (const float*)d_in[6];
    const float* offset_scale = (const float*)d_in[7];
    float* out = (float*)d_out;
    float* ws  = (float*)d_ws;

    if (ws_size >= NEW_WS_BYTES) {
        float* xt       = ws;
        float* partials = ws + PART_OFF;
        float* stats    = ws + STATS_OFF;
        transpose_x<<<BB * GRP * HW / 256, 256, 0, stream>>>(x, xt);
        dcn_fused2<<<BB * GRP * 64, 256, 0, stream>>>(x, xt, w_om, b_om, dcn_w,
                                                      dcn_b, offset_scale, out,
                                                      partials);
        gn_finalize<<<BB * GRP, 64, 0, stream>>>(partials, stats);
        gn_gelu<<<(BB * C_OUT * HW / 4) / 256, 256, 0, stream>>>(out, stats,
                                                                 gn_w, gn_b);
    } else {
        float* stats = ws;  // 32 floats
        dcn_fused_fb<<<BB * GRP * 64, 256, 0, stream>>>(x, w_om, b_om, dcn_w,
                                                        dcn_b, offset_scale, out);
        gn_stats_fb<<<BB * GRP, 256, 0, stream>>>(out, stats);
        gn_gelu<<<(BB * C_OUT * HW / 4) / 256, 256, 0, stream>>>(out, stats,
                                                                 gn_w, gn_b);
    }
}

// Round 3
// 87.618 us; speedup vs baseline: 2.2236x; 1.0746x over previous
//
#include <hip/hip_runtime.h>
#include <math.h>

#define GRP   4
#define K     9
#define PAD   1
#define C_IN  64
#define C_OUT 64
#define CG    16
#define HH    128
#define WW    128
#define BB    4
#define HW    (HH*WW)
#define OMG   27

// ws layout: xt (bf16, 16 bg * HW * 16 = 8,388,608 B) | partials (2048*2 f32) | stats (32 f32)
#define XT_BYTES   ((size_t)16 * HW * 16 * 2)
#define PART_OFF_B XT_BYTES
#define STATS_OFF_B (XT_BYTES + 2048 * 2 * sizeof(float))

// ---- K0: x[B,64,H,W] -> xt[bg][pix][16] in bf16 (RTNE) ----------------------
__global__ __launch_bounds__(256) void transpose_pack(const float* __restrict__ x,
                                                      ushort* __restrict__ xt)
{
    const int t   = blockIdx.x * 256 + threadIdx.x;    // 262144
    const int pix = t & (HW - 1);
    const int bg  = t >> 14;
    const int b   = bg >> 2;
    const int g   = bg & 3;
    const float* xs = x + ((size_t)b * C_IN + g * CG) * HW + pix;
    uint p[8];
    #pragma unroll
    for (int q = 0; q < 8; ++q) {
        float f0 = xs[(size_t)(2*q)   * HW];
        float f1 = xs[(size_t)(2*q+1) * HW];
        uint u0 = __float_as_uint(f0);
        uint u1 = __float_as_uint(f1);
        u0 = (u0 + 0x7fffu + ((u0 >> 16) & 1u)) >> 16;   // RTNE bf16
        u1 = (u1 + 0x7fffu + ((u1 >> 16) & 1u)) >> 16;
        p[q] = u0 | (u1 << 16);
    }
    uint4* dst = (uint4*)(xt + ((size_t)bg * HW + pix) * 16);
    dst[0] = make_uint4(p[0], p[1], p[2], p[3]);
    dst[1] = make_uint4(p[4], p[5], p[6], p[7]);
}

// ---- K1: fused om-conv + deformable conv + GN partials ----------------------
// 2048 blocks x 256 thr. Block = (bg, row). Thread-pairs (adjacent lanes) split
// one pixel: stage1 by c-half, gather by ci-half, matmul by co-half.
__global__ __launch_bounds__(256, 4) void dcn_main(
    const float*  __restrict__ x,
    const ushort* __restrict__ xt,
    const float*  __restrict__ w_om,
    const float*  __restrict__ b_om,
    const float*  __restrict__ dcn_w,
    const float*  __restrict__ dcn_b,
    const float*  __restrict__ offset_scale,
    float* __restrict__ out,
    float* __restrict__ partials)
{
    const int tid = threadIdx.x;
    const int bid = blockIdx.x;
    // XCD-friendly: xcd = bid&7 handles bg {2*xcd, 2*xcd+1}
    const int xcd = bid & 7;
    const int i   = bid >> 3;            // 0..255
    const int bg  = xcd * 2 + (i >> 7);
    const int row = i & 127;
    const int b   = bg >> 2;
    const int g   = bg & 3;

    const int wave = tid >> 6;
    const int lane = tid & 63;
    const int pr   = lane >> 1;          // pair index 0..31
    const int half = lane & 1;
    const int pcol = wave * 32 + pr;     // 0..127
    const int pix  = row * WW + pcol;

    __shared__ float s_wom[C_IN * 32];   // [c][32] (27 used) 8192 B
    __shared__ float s_w[K * CG * CG];   // [k][ci][co]       9216 B
    __shared__ float s_bom[28];
    __shared__ float s_bw[CG];
    __shared__ float exch[4][32][36];    // pair-exchange, stride 36 for banks
    __shared__ float red[512];

    for (int idx = tid; idx < C_IN * 32; idx += 256) {
        int c = idx >> 5, o = idx & 31;
        s_wom[idx] = (o < OMG) ? w_om[(g * OMG + o) * C_IN + c] : 0.0f;
    }
    for (int idx = tid; idx < K * CG * CG; idx += 256) {
        int k = idx >> 8, ci = (idx >> 4) & 15, co = idx & 15;
        s_w[idx] = dcn_w[((g * CG + co) * CG + ci) * K + k];
    }
    if (tid < 28) s_bom[tid] = (tid < OMG) ? b_om[g * OMG + tid] : 0.0f;
    if (tid < CG) s_bw[tid]  = dcn_b[g * CG + tid];
    __syncthreads();

    // ---- stage 1: om partial over this half's 32 channels ----
    float om[28];
    #pragma unroll
    for (int o = 0; o < 28; ++o) om[o] = 0.0f;
    const float* xp = x + (size_t)b * C_IN * HW + pix;
    const int c0 = half * 32;
    #pragma unroll 4
    for (int ci = 0; ci < 32; ++ci) {
        float xv = xp[(size_t)(c0 + ci) * HW];
        const float4* wp = (const float4*)&s_wom[(c0 + ci) * 32];
        #pragma unroll
        for (int q = 0; q < 7; ++q) {
            float4 w4 = wp[q];
            om[q*4+0] += w4.x * xv;
            om[q*4+1] += w4.y * xv;
            om[q*4+2] += w4.z * xv;
            om[q*4+3] += w4.w * xv;
        }
    }

    // ---- pair exchange of om partials (wave-local, no barrier) ----
    float* slot = &exch[wave][pr][0];
    if (half == 1) {
        #pragma unroll
        for (int o = 0; o < 28; ++o) slot[o] = om[o];
    }
    __builtin_amdgcn_wave_barrier();
    if (half == 0) {
        #pragma unroll
        for (int o = 0; o < 28; ++o) om[o] += slot[o];
        #pragma unroll
        for (int o = 0; o < OMG; ++o) om[o] += s_bom[o];
        #pragma unroll
        for (int o = 0; o < OMG; ++o) slot[o] = om[o];
    }
    __builtin_amdgcn_wave_barrier();
    if (half == 1) {
        #pragma unroll
        for (int o = 0; o < OMG; ++o) om[o] = slot[o];
    }
    __builtin_amdgcn_wave_barrier();

    const float scale = offset_scale[0];
    float py[9], px[9], msk[9];
    #pragma unroll
    for (int k = 0; k < 9; ++k) {
        py[k]  = (float)(row  - PAD + k / 3) + om[2*k]     * scale;
        px[k]  = (float)(pcol - PAD + k % 3) + om[2*k + 1] * scale;
        msk[k] = 1.0f / (1.0f + __expf(-om[18 + k]));
    }

    // ---- stage 2: sample (bf16 xt), pair-exchange vals, 16ci x 8co matmul ----
    float acc[8];
    #pragma unroll
    for (int j = 0; j < 8; ++j) acc[j] = s_bw[half * 8 + j];

    const ushort* xtg = xt + (size_t)bg * HW * 16 + half * 8;
    float* vslot = &exch[wave][pr][0];

    #pragma unroll
    for (int k = 0; k < 9; ++k) {
        float y0f = floorf(py[k]), x0f = floorf(px[k]);
        int   y0  = (int)y0f,      x0  = (int)x0f;
        float wy1 = py[k] - y0f,   wx1 = px[k] - x0f;
        float wy0 = 1.0f - wy1,    wx0 = 1.0f - wx1;

        bool vy0 = (y0   >= 0) && (y0   <= HH - 1);
        bool vy1 = (y0+1 >= 0) && (y0+1 <= HH - 1);
        bool vx0 = (x0   >= 0) && (x0   <= WW - 1);
        bool vx1 = (x0+1 >= 0) && (x0+1 <= WW - 1);

        int yi0 = min(max(y0,     0), HH - 1);
        int yi1 = min(max(y0 + 1, 0), HH - 1);
        int xi0 = min(max(x0,     0), WW - 1);
        int xi1 = min(max(x0 + 1, 0), WW - 1);

        float w00 = (vy0 && vx0) ? wy0 * wx0 * msk[k] : 0.0f;
        float w01 = (vy0 && vx1) ? wy0 * wx1 * msk[k] : 0.0f;
        float w10 = (vy1 && vx0) ? wy1 * wx0 * msk[k] : 0.0f;
        float w11 = (vy1 && vx1) ? wy1 * wx1 * msk[k] : 0.0f;

        uint4 t00 = *(const uint4*)(xtg + (size_t)(yi0 * WW + xi0) * 16);
        uint4 t01 = *(const uint4*)(xtg + (size_t)(yi0 * WW + xi1) * 16);
        uint4 t10 = *(const uint4*)(xtg + (size_t)(yi1 * WW + xi0) * 16);
        uint4 t11 = *(const uint4*)(xtg + (size_t)(yi1 * WW + xi1) * 16);

        float vloc[8];
        #pragma unroll
        for (int d = 0; d < 4; ++d) {
            uint u00 = ((const uint*)&t00)[d], u01 = ((const uint*)&t01)[d];
            uint u10 = ((const uint*)&t10)[d], u11 = ((const uint*)&t11)[d];
            float a0 = __uint_as_float(u00 << 16), a1 = __uint_as_float(u00 & 0xffff0000u);
            float b0 = __uint_as_float(u01 << 16), b1 = __uint_as_float(u01 & 0xffff0000u);
            float c0f= __uint_as_float(u10 << 16), c1 = __uint_as_float(u10 & 0xffff0000u);
            float d0 = __uint_as_float(u11 << 16), d1 = __uint_as_float(u11 & 0xffff0000u);
            vloc[2*d]   = w00*a0 + w01*b0 + w10*c0f + w11*d0;
            vloc[2*d+1] = w00*a1 + w01*b1 + w10*c1  + w11*d1;
        }

        // pair exchange of the 8 sampled channels (wave-local)
        float4* vw = (float4*)(vslot + half * 8);
        vw[0] = make_float4(vloc[0], vloc[1], vloc[2], vloc[3]);
        vw[1] = make_float4(vloc[4], vloc[5], vloc[6], vloc[7]);
        __builtin_amdgcn_wave_barrier();

        #pragma unroll
        for (int ci = 0; ci < CG; ++ci) {
            float v = vslot[ci];
            const float4* wrow = (const float4*)&s_w[(k * CG + ci) * CG + half * 8];
            float4 wa = wrow[0], wb = wrow[1];
            acc[0] += v * wa.x; acc[1] += v * wa.y;
            acc[2] += v * wa.z; acc[3] += v * wa.w;
            acc[4] += v * wb.x; acc[5] += v * wb.y;
            acc[6] += v * wb.z; acc[7] += v * wb.w;
        }
        __builtin_amdgcn_wave_barrier();
    }

    // ---- write out + GN partials ----
    const size_t obase = ((size_t)b * C_OUT + g * CG + half * 8) * HW + pix;
    float s = 0.0f, ss = 0.0f;
    #pragma unroll
    for (int j = 0; j < 8; ++j) {
        out[obase + (size_t)j * HW] = acc[j];
        s  += acc[j];
        ss += acc[j] * acc[j];
    }
    red[tid] = s; red[256 + tid] = ss;
    __syncthreads();
    for (int st = 128; st > 0; st >>= 1) {
        if (tid < st) {
            red[tid]       += red[tid + st];
            red[256 + tid] += red[256 + tid + st];
        }
        __syncthreads();
    }
    if (tid == 0) {
        partials[(bg * 128 + row) * 2]     = red[0];
        partials[(bg * 128 + row) * 2 + 1] = red[256];
    }
}

// ---- K2: finalize GN stats (16 blocks x 64 lanes) ---------------------------
__global__ __launch_bounds__(64) void gn_finalize(const float* __restrict__ partials,
                                                  float* __restrict__ stats)
{
    const int bg = blockIdx.x;
    const int t  = threadIdx.x;
    float s  = partials[(bg * 128 + 2*t) * 2]     + partials[(bg * 128 + 2*t + 1) * 2];
    float ss = partials[(bg * 128 + 2*t) * 2 + 1] + partials[(bg * 128 + 2*t + 1) * 2 + 1];
    #pragma unroll
    for (int off = 32; off > 0; off >>= 1) {
        s  += __shfl_down(s, off);
        ss += __shfl_down(ss, off);
    }
    if (t == 0) {
        float n   = (float)(CG * HW);
        float mu  = s / n;
        float var = ss / n - mu * mu;
        stats[bg * 2]     = mu;
        stats[bg * 2 + 1] = rsqrtf(var + 1e-5f);
    }
}

// ---- K3: in-place GroupNorm apply + exact GELU ------------------------------
__global__ __launch_bounds__(256) void gn_gelu(float* __restrict__ out,
                                               const float* __restrict__ stats,
                                               const float* __restrict__ gn_w,
                                               const float* __restrict__ gn_b)
{
    const int idx = blockIdx.x * 256 + threadIdx.x;   // float4 index
    const int bc  = idx >> 12;                        // b*64 + c
    const int c   = bc & 63;
    const int bg  = ((bc >> 6) << 2) + (c >> 4);

    float mu = stats[bg * 2];
    float rs = stats[bg * 2 + 1];
    float sw = gn_w[c] * rs;
    float sb = gn_b[c] - mu * sw;

    float4 v = ((const float4*)out)[idx];
    float rr[4] = {v.x, v.y, v.z, v.w};
    #pragma unroll
    for (int jj = 0; jj < 4; ++jj) {
        float t = rr[jj] * sw + sb;
        rr[jj] = t * 0.5f * (1.0f + erff(t * 0.70710678118654752f));
    }
    ((float4*)out)[idx] = make_float4(rr[0], rr[1], rr[2], rr[3]);
}

// ============================ launch =========================================

extern "C" void kernel_launch(void* const* d_in, const int* in_sizes, int n_in,
                              void* d_out, int out_size, void* d_ws, size_t ws_size,
                              hipStream_t stream) {
    const float* x            = (const float*)d_in[0];
    const float* w_om         = (const float*)d_in[1];
    const float* b_om         = (const float*)d_in[2];
    const float* dcn_w        = (const float*)d_in[3];
    const float* dcn_b        = (const float*)d_in[4];
    const float* gn_w         = (const float*)d_in[5];
    const float* gn_b         = (const float*)d_in[6];
    const float* offset_scale = (const float*)d_in[7];
    float* out = (float*)d_out;

    ushort* xt      = (ushort*)d_ws;
    float* partials = (float*)((char*)d_ws + PART_OFF_B);
    float* stats    = (float*)((char*)d_ws + STATS_OFF_B);

    transpose_pack<<<BB * GRP * HW / 256, 256, 0, stream>>>(x, xt);
    dcn_main<<<2048, 256, 0, stream>>>(x, xt, w_om, b_om, dcn_w, dcn_b,
                                       offset_scale, out, partials);
    gn_finalize<<<16, 64, 0, stream>>>(partials, stats);
    gn_gelu<<<(BB * C_OUT * HW / 4) / 256, 256, 0, stream>>>(out, stats, gn_w, gn_b);
}

// Round 4
// 79.026 us; speedup vs baseline: 2.4654x; 1.1087x over previous
//
#include <hip/hip_runtime.h>
#include <math.h>

#define GRP   4
#define K     9
#define PAD   1
#define C_IN  64
#define CG    16
#define HH    128
#define WW    128
#define BB    4
#define HW    (HH*WW)

typedef __attribute__((ext_vector_type(8))) _Float16 f16x8;
typedef __attribute__((ext_vector_type(4))) float    f32x4;

union F16Frag { f16x8 f; _Float16 h[8]; uint w[4]; uint4 q; };

// ws layout: xt fp16 [B][HW][64] = 8,388,608 B | partials 1024*2 f32 | stats 32 f32
#define XT_HALFS   ((size_t)BB * HW * 64)
#define PART_OFF_B (XT_HALFS * 2)
#define STATS_OFF_B (PART_OFF_B + 1024 * 2 * sizeof(float))

// ---- K0: x[B,64,H,W] -> xt[b][pix][64] fp16 ---------------------------------
// thread = (b, pix, channel-quarter). Stores are fully coalesced (1KB/wave).
__global__ __launch_bounds__(256) void transpose_pack(const float* __restrict__ x,
                                                      _Float16* __restrict__ xt)
{
    const int t   = blockIdx.x * 256 + threadIdx.x;   // 262144
    const int qq  = t & 3;
    const int p2  = t >> 2;
    const int pix = p2 & (HW - 1);
    const int b   = p2 >> 14;
    const float* xs = x + ((size_t)b * C_IN + qq * 16) * HW + pix;
    F16Frag f0, f1;
    #pragma unroll
    for (int j = 0; j < 8; ++j) f0.h[j] = (_Float16)xs[(size_t)j * HW];
    #pragma unroll
    for (int j = 0; j < 8; ++j) f1.h[j] = (_Float16)xs[(size_t)(8 + j) * HW];
    uint4* dst = (uint4*)(xt + ((size_t)b * HW + pix) * 64 + qq * 16);
    dst[0] = f0.q;
    dst[1] = f1.q;
}

// ---- K1: MFMA-based fused om-conv + deformable conv + GN partials -----------
// 1024 blocks x 256 thr (4 waves). Block = (bg, 256-pixel chunk). Wave = 64 px,
// processed as 4 tiles of 16. Per tile: stage1 = 4 MFMA (K=64, N=32) producing
// om; redistribute via om_lds; stage2 = 5 MFMA (K=160 padded from 144, N=16co).
__global__ __launch_bounds__(256, 4) void dcn_mfma(
    const _Float16* __restrict__ xt,
    const float* __restrict__ w_om,
    const float* __restrict__ b_om,
    const float* __restrict__ dcn_w,     // [G][16co][16ci][9]
    const float* __restrict__ dcn_b,
    const float* __restrict__ offset_scale,
    float* __restrict__ out,
    float* __restrict__ partials)
{
    const int tid = threadIdx.x;
    const int blk = blockIdx.x;
    const int xcd = blk & 7;
    const int q   = blk >> 3;
    const int bg  = xcd * 2 + (q >> 6);
    const int tb  = q & 63;              // 256-pixel chunk within bg
    const int b   = bg >> 2, g = bg & 3;
    const int wave = tid >> 6, lane = tid & 63;
    const int lr = lane & 15;            // fragment row/col index
    const int lj = lane >> 4;            // k-group 0..3

    __shared__ float om_lds[4][16][33];  // per-wave slab, stride 33 = no conflicts
    __shared__ float red[512];

    // ---- B1 fragments (om weights, fp16, registers): [kstep s][ntile nt] ----
    // B1[ch][o]: col o = nt*16+lr, elems e: ch = s*32 + lj*8 + e (contiguous)
    F16Frag B1[2][2];
    #pragma unroll
    for (int s = 0; s < 2; ++s)
    #pragma unroll
    for (int nt = 0; nt < 2; ++nt) {
        const int o = nt * 16 + lr;
        if (o < 27) {
            const float* src = w_om + (size_t)(g * 27 + o) * C_IN + s * 32 + lj * 8;
            #pragma unroll
            for (int e = 0; e < 8; ++e) B1[s][nt].h[e] = (_Float16)src[e];
        } else {
            #pragma unroll
            for (int e = 0; e < 4; ++e) B1[s][nt].w[e] = 0u;
        }
    }
    // ---- B2 fragments (dcn weights): reduction idx = kpoint*16 + ci ----------
    // col co = lr; elems e: idx = s*32 + lj*8 + e -> kp = 2s+(lj>>1), ci=(lj&1)*8+e
    F16Frag B2[5];
    #pragma unroll
    for (int s = 0; s < 5; ++s) {
        const int kp  = 2 * s + (lj >> 1);
        const int cib = (lj & 1) * 8;
        if (kp < 9) {
            const float* src = dcn_w + ((size_t)(g * CG + lr) * CG + cib) * 9 + kp;
            #pragma unroll
            for (int e = 0; e < 8; ++e) B2[s].h[e] = (_Float16)src[(size_t)e * 9];
        } else {
            #pragma unroll
            for (int e = 0; e < 4; ++e) B2[s].w[e] = 0u;
        }
    }

    const float scale = offset_scale[0];
    const float bo0   = b_om[g * 27 + lr];
    const float bo1   = (lr < 11) ? b_om[g * 27 + 16 + lr] : 0.0f;
    const float cbias = dcn_b[g * CG + lr];

    const _Float16* xtb = xt + (size_t)b * HW * 64;
    const _Float16* xg  = xtb + g * CG + (lj & 1) * 8;   // tap base (ci-half slice)
    const int pixw = tb * 256 + wave * 64;
    float gs = 0.0f, gss = 0.0f;

    for (int t = 0; t < 4; ++t) {
        const int pix0 = pixw + t * 16;
        const int row  = pix0 >> 7;
        const int col0 = pix0 & 127;

        // ---- stage 1: om GEMM (A = xt[16pix][64ch], B = w_om) ----
        f32x4 C0 = {0, 0, 0, 0}, C1 = {0, 0, 0, 0};
        #pragma unroll
        for (int s = 0; s < 2; ++s) {
            F16Frag A;
            A.q = *(const uint4*)(xtb + (size_t)(pix0 + lr) * 64 + s * 32 + lj * 8);
            C0 = __builtin_amdgcn_mfma_f32_16x16x32_f16(A.f, B1[s][0].f, C0, 0, 0, 0);
            C1 = __builtin_amdgcn_mfma_f32_16x16x32_f16(A.f, B1[s][1].f, C1, 0, 0, 0);
        }
        // epilogue: lane holds (o = lr | 16+lr, 4 pixels). transform + scatter.
        #pragma unroll
        for (int r = 0; r < 4; ++r) {
            const int prow = lj * 4 + r;
            om_lds[wave][prow][lr] = (C0[r] + bo0) * scale;        // o<16: offsets
            const float v1 = C1[r] + bo1;
            const int o1 = 16 + lr;
            om_lds[wave][prow][o1] = (o1 < 18) ? v1 * scale        // o 16,17
                                   : 1.0f / (1.0f + __expf(-v1));  // o>=18: mask
        }

        // ---- stage 2: sample + deform-conv GEMM ----
        f32x4 C2 = {cbias, cbias, cbias, cbias};
        #pragma unroll
        for (int s = 0; s < 5; ++s) {
            const int  kp  = 2 * s + (lj >> 1);
            const bool kok = (kp < 9);
            const int  kc  = kok ? kp : 8;
            const float offy = om_lds[wave][lr][2 * kc];
            const float offx = om_lds[wave][lr][2 * kc + 1];
            const float m    = kok ? om_lds[wave][lr][18 + kc] : 0.0f;
            const float py = (float)(row  - PAD + kc / 3) + offy;
            const float px = (float)(col0 + lr - PAD + kc % 3) + offx;

            const float y0f = floorf(py), x0f = floorf(px);
            const int   y0  = (int)y0f,   x0  = (int)x0f;
            const float wy1 = py - y0f,   wx1 = px - x0f;
            const float wy0 = 1.0f - wy1, wx0 = 1.0f - wx1;
            const bool vy0 = (y0 >= 0)  & (y0 <  HH);
            const bool vy1 = (y0 >= -1) & (y0 <  HH - 1);
            const bool vx0 = (x0 >= 0)  & (x0 <  WW);
            const bool vx1 = (x0 >= -1) & (x0 <  WW - 1);
            const int yi0 = min(max(y0,     0), HH - 1);
            const int yi1 = min(max(y0 + 1, 0), HH - 1);
            const int xi0 = min(max(x0,     0), WW - 1);
            const int xi1 = min(max(x0 + 1, 0), WW - 1);
            const float w00 = (vy0 & vx0) ? wy0 * wx0 * m : 0.0f;
            const float w01 = (vy0 & vx1) ? wy0 * wx1 * m : 0.0f;
            const float w10 = (vy1 & vx0) ? wy1 * wx0 * m : 0.0f;
            const float w11 = (vy1 & vx1) ? wy1 * wx1 * m : 0.0f;

            F16Frag t00, t01, t10, t11;
            t00.q = *(const uint4*)(xg + (size_t)(yi0 * WW + xi0) * 64);
            t01.q = *(const uint4*)(xg + (size_t)(yi0 * WW + xi1) * 64);
            t10.q = *(const uint4*)(xg + (size_t)(yi1 * WW + xi0) * 64);
            t11.q = *(const uint4*)(xg + (size_t)(yi1 * WW + xi1) * 64);

            F16Frag A;
            #pragma unroll
            for (int e = 0; e < 8; ++e) {
                const float v = w00 * (float)t00.h[e] + w01 * (float)t01.h[e]
                              + w10 * (float)t10.h[e] + w11 * (float)t11.h[e];
                A.h[e] = (_Float16)v;
            }
            C2 = __builtin_amdgcn_mfma_f32_16x16x32_f16(A.f, B2[s].f, C2, 0, 0, 0);
        }

        // ---- store (lane: co = lr, pixels lj*4+r) + GN accumulation ----
        float4 st;
        #pragma unroll
        for (int r = 0; r < 4; ++r) {
            const float v = C2[r];
            gs += v; gss += v * v;
            (&st.x)[r] = v;
        }
        *(float4*)(out + ((size_t)b * 64 + g * CG + lr) * HW + pix0 + lj * 4) = st;
    }

    // ---- block GN partial reduction ----
    red[tid] = gs; red[256 + tid] = gss;
    __syncthreads();
    for (int st2 = 128; st2 > 0; st2 >>= 1) {
        if (tid < st2) {
            red[tid]       += red[tid + st2];
            red[256 + tid] += red[256 + tid + st2];
        }
        __syncthreads();
    }
    if (tid == 0) {
        partials[(bg * 64 + tb) * 2]     = red[0];
        partials[(bg * 64 + tb) * 2 + 1] = red[256];
    }
}

// ---- K2: finalize GN stats --------------------------------------------------
__global__ __launch_bounds__(64) void gn_finalize(const float* __restrict__ partials,
                                                  float* __restrict__ stats)
{
    const int bg = blockIdx.x;
    const int t  = threadIdx.x;
    float s  = partials[(bg * 64 + t) * 2];
    float ss = partials[(bg * 64 + t) * 2 + 1];
    #pragma unroll
    for (int off = 32; off > 0; off >>= 1) {
        s  += __shfl_down(s, off);
        ss += __shfl_down(ss, off);
    }
    if (t == 0) {
        const float n   = (float)(CG * HW);
        const float mu  = s / n;
        const float var = ss / n - mu * mu;
        stats[bg * 2]     = mu;
        stats[bg * 2 + 1] = rsqrtf(var + 1e-5f);
    }
}

// ---- K3: in-place GroupNorm apply + exact GELU ------------------------------
__global__ __launch_bounds__(256) void gn_gelu(float* __restrict__ out,
                                               const float* __restrict__ stats,
                                               const float* __restrict__ gn_w,
                                               const float* __restrict__ gn_b)
{
    const int idx = blockIdx.x * 256 + threadIdx.x;   // float4 index
    const int bc  = idx >> 12;
    const int c   = bc & 63;
    const int bg  = ((bc >> 6) << 2) + (c >> 4);

    const float mu = stats[bg * 2];
    const float rs = stats[bg * 2 + 1];
    const float sw = gn_w[c] * rs;
    const float sb = gn_b[c] - mu * sw;

    float4 v = ((const float4*)out)[idx];
    float rr[4] = {v.x, v.y, v.z, v.w};
    #pragma unroll
    for (int jj = 0; jj < 4; ++jj) {
        const float t = rr[jj] * sw + sb;
        rr[jj] = t * 0.5f * (1.0f + erff(t * 0.70710678118654752f));
    }
    ((float4*)out)[idx] = make_float4(rr[0], rr[1], rr[2], rr[3]);
}

// ============================ launch =========================================

extern "C" void kernel_launch(void* const* d_in, const int* in_sizes, int n_in,
                              void* d_out, int out_size, void* d_ws, size_t ws_size,
                              hipStream_t stream) {
    const float* x            = (const float*)d_in[0];
    const float* w_om         = (const float*)d_in[1];
    const float* b_om         = (const float*)d_in[2];
    const float* dcn_w        = (const float*)d_in[3];
    const float* dcn_b        = (const float*)d_in[4];
    const float* gn_w         = (const float*)d_in[5];
    const float* gn_b         = (const float*)d_in[6];
    const float* offset_scale = (const float*)d_in[7];
    float* out = (float*)d_out;

    _Float16* xt    = (_Float16*)d_ws;
    float* partials = (float*)((char*)d_ws + PART_OFF_B);
    float* stats    = (float*)((char*)d_ws + STATS_OFF_B);

    transpose_pack<<<1024, 256, 0, stream>>>(x, xt);
    dcn_mfma<<<1024, 256, 0, stream>>>(xt, w_om, b_om, dcn_w, dcn_b,
                                       offset_scale, out, partials);
    gn_finalize<<<16, 64, 0, stream>>>(partials, stats);
    gn_gelu<<<(BB * 64 * HW / 4) / 256, 256, 0, stream>>>(out, stats, gn_w, gn_b);
}